// Round 7
// baseline (19093.654 us; speedup 1.0000x reference)
//
#include <hip/hip_runtime.h>

// Encoder: 2-layer LSTM (H1=64, H2=32, IN=2), B=512, T=4096, + FC [32->16].
// R7 = R6 design with (a) macro token-pasting bug fixed (pp-number `2.y`
// gotcha -> weight regs now passed as macro ARGS, no pasting) and (b) octet
// combine fixed: row_shl:4 (0x104), so lanes s2<4 hold the full 96-dot and
// the s2==0 writer is valid (R6 used row_shr:4 which left totals in s2>=4).
//
// Design: K-sliced reduction GEMV, pressure fits under the 128-VGPR rung so
// weight residency is the allocator's DEFAULT (R2-R5 showed >128-float weight
// sets get stripped back into per-step reloads regardless of pins):
//   - 512-thr blocks (8 waves): waves 4..7 = L1: quad of lanes = 1 unit,
//     lane slice = 16 of K=64 -> 64 weight floats/lane (16 named f4).
//     waves 0..3 = L2: octet = 1 unit, slice = 12 of K=96, one step behind.
//   - 4 gate rows = 4 reduction passes; DPP butterfly (xor1, xor2 [,shl4])
//     leaves ALL 4 pre-activations in every lane -> no gate-exchange shuffles.
//   - h broadcast: 3-5 ds_read_b128/wave/step (same-address broadcast = free)
//     instead of 64-96 readlanes.
//   - in-loop asm pins: per-iteration asm defs can't be rematerialized.

#define TT 4096
#define BB 512

typedef float f4 __attribute__((ext_vector_type(4)));

__device__ __forceinline__ float fexp2(float x){ return __builtin_amdgcn_exp2f(x); }
__device__ __forceinline__ float frcp (float x){ return __builtin_amdgcn_rcpf(x); }
__device__ __forceinline__ float sigm (float x){ return frcp(1.0f + fexp2(x * -1.4426950408889634f)); }
__device__ __forceinline__ float tanh_(float x){ return 1.0f - 2.0f * frcp(1.0f + fexp2(x * 2.8853900817779268f)); }

__device__ __forceinline__ float rlane(float v, int lane){
  return __builtin_bit_cast(float, __builtin_amdgcn_readlane(__builtin_bit_cast(int, v), lane));
}
// v + DPP-permuted v. 0xB1 = quad xor1, 0x4E = quad xor2, 0x104 = row_shl:4.
// bound_ctrl=1: out-of-range source lanes contribute 0.
template<int CTRL>
__device__ __forceinline__ float dadd(float v){
  const int s = __builtin_bit_cast(int, v);
  const int p = __builtin_amdgcn_update_dpp(s, s, CTRL, 0xF, 0xF, true);
  return v + __builtin_bit_cast(float, p);
}

#define PIN4(a,b,c,d) asm volatile("" : "+v"(a), "+v"(b), "+v"(c), "+v"(d))

extern "C" __global__ __launch_bounds__(512, 4) void lstm_enc_kernel(
    const float* __restrict__ x,
    const float* __restrict__ Wih1, const float* __restrict__ Whh1,
    const float* __restrict__ bih1, const float* __restrict__ bhh1,
    const float* __restrict__ Wih2, const float* __restrict__ Whh2,
    const float* __restrict__ bih2, const float* __restrict__ bhh2,
    const float* __restrict__ Wfc,  const float* __restrict__ bfc,
    float* __restrict__ out)
{
    const int tid = threadIdx.x;
    const int l   = tid & 63;
    const int wv  = __builtin_amdgcn_readfirstlane(tid >> 6);   // 0..7, scalar
    const bool isL1 = (wv >= 4);
    const int b   = blockIdx.x;

    __shared__ float h1s[2][64];
    __shared__ float h2s[2][32];

    // L1: quad = unit, slice s1 = quarter of K=64 (16 floats)
    const int u1 = (wv & 3) * 16 + (l >> 2);
    const int s1 = l & 3;
    // L2: octet = unit, slice s2 = eighth of K=96 (8 h1-floats + 4 h2-floats)
    const int u2 = (wv & 3) * 8 + (l >> 3);
    const int s2 = l & 7;

    const f4* Wh1p = (const f4*)Whh1;   // [256][16] f4
    const f4* Wi2p = (const f4*)Wih2;   // [128][16] f4
    const f4* Wh2p = (const f4*)Whh2;   // [128][8]  f4

    f4 w00,w01,w02,w03, w10,w11,w12,w13, w20,w21,w22,w23, w30,w31,w32,w33;
    float bb0,bb1,bb2,bb3;
    float wx00,wx01, wx10,wx11, wx20,wx21, wx30,wx31;

    // unconditional loads, role-selected addresses (all in-bounds both roles)
#define LOADW(G, W0,W1,W2,W3, BBG, WX0, WX1) { \
    const int rg1 = (G)*64 + u1; const int rg2 = (G)*32 + u2; \
    const int i1  = rg1*16 + 4*s1; \
    W0 = *(isL1 ? (Wh1p + i1)     : (Wi2p + rg2*16 + 2*s2)); \
    W1 = *(isL1 ? (Wh1p + i1 + 1) : (Wi2p + rg2*16 + 2*s2 + 1)); \
    W2 = *(isL1 ? (Wh1p + i1 + 2) : (Wh2p + rg2*8 + s2)); \
    W3 = *(isL1 ? (Wh1p + i1 + 3) : (Wh2p + rg2*8 + s2)); \
    BBG = isL1 ? (bih1[rg1] + bhh1[rg1]) : (bih2[rg2] + bhh2[rg2]); \
    WX0 = Wih1[rg1*2]; WX1 = Wih1[rg1*2 + 1]; }

    LOADW(0, w00,w01,w02,w03, bb0, wx00,wx01)
    LOADW(1, w10,w11,w12,w13, bb1, wx10,wx11)
    LOADW(2, w20,w21,w22,w23, bb2, wx20,wx21)
    LOADW(3, w30,w31,w32,w33, bb3, wx30,wx31)
#undef LOADW

    const float2* xb2 = (const float2*)(x + (size_t)b * (TT * 2));
    float2 vx = make_float2(0.f, 0.f), vxn = make_float2(0.f, 0.f);
    if (isL1) vxn = xb2[l];                   // chunk 0 (64 steps of x)

    if (tid < 64) h1s[0][tid] = 0.f;
    if (tid < 32) { h2s[0][tid] = 0.f; h2s[1][tid] = 0.f; }
    __syncthreads();

    float cc = 0.f;   // cell state: c1 for L1 lanes, c2 for L2 lanes

    // L1 pass: 16-float slice dot (4 f4), quad butterfly -> full 64-dot
#define PASS1(W0,W1,W2,W3, BBG, WX0, WX1, PRE) { \
    float a0 = W0.x*A0.x, a1 = W0.y*A0.y, a2 = W0.z*A0.z, a3 = W0.w*A0.w; \
    a0 = fmaf(W1.x, A1.x, a0); a1 = fmaf(W1.y, A1.y, a1); \
    a2 = fmaf(W1.z, A1.z, a2); a3 = fmaf(W1.w, A1.w, a3); \
    a0 = fmaf(W2.x, A2.x, a0); a1 = fmaf(W2.y, A2.y, a1); \
    a2 = fmaf(W2.z, A2.z, a2); a3 = fmaf(W2.w, A2.w, a3); \
    a0 = fmaf(W3.x, A3.x, a0); a1 = fmaf(W3.y, A3.y, a1); \
    a2 = fmaf(W3.z, A3.z, a2); a3 = fmaf(W3.w, A3.w, a3); \
    float hs = (a0 + a1) + (a2 + a3); \
    hs = dadd<0xB1>(hs); hs = dadd<0x4E>(hs); \
    PRE = fmaf(WX0, xx0, fmaf(WX1, xx1, hs + BBG)); }

    // L2 pass: 12-float slice dot (3 f4), quad butterfly + row_shl:4 ->
    // full 96-dot valid in lanes with (l&7) < 4 (incl. the s2==0 writer)
#define PASS2(W0,W1,W2, BBG, PRE) { \
    float a0 = W0.x*B0.x, a1 = W0.y*B0.y, a2 = W0.z*B0.z, a3 = W0.w*B0.w; \
    a0 = fmaf(W1.x, B1.x, a0); a1 = fmaf(W1.y, B1.y, a1); \
    a2 = fmaf(W1.z, B1.z, a2); a3 = fmaf(W1.w, B1.w, a3); \
    a0 = fmaf(W2.x, C0.x, a0); a1 = fmaf(W2.y, C0.y, a1); \
    a2 = fmaf(W2.z, C0.z, a2); a3 = fmaf(W2.w, C0.w, a3); \
    float hs = (a0 + a1) + (a2 + a3); \
    hs = dadd<0xB1>(hs); hs = dadd<0x4E>(hs); hs = dadd<0x104>(hs); \
    PRE = hs + BBG; }

    // t in [0, TT]: L1 computes step t (t<TT); L2 computes step t-1 (t>0).
    for (int t = 0; t <= TT; ++t) {
        const int rb = t & 1;
        const int wb = rb ^ 1;

        if (isL1) {
            if (t < TT) {
                PIN4(w00,w01,w02,w03); PIN4(w10,w11,w12,w13);
                PIN4(w20,w21,w22,w23); PIN4(w30,w31,w32,w33);
                if ((t & 63) == 0) {
                    vx = vxn;
                    if (t + 64 < TT) vxn = xb2[(t >> 6) * 64 + 64 + l];
                }
                const float xx0 = rlane(vx.x, t & 63);
                const float xx1 = rlane(vx.y, t & 63);
                // h1(t-1) slice [16*s1, 16*s1+16)
                const f4* hb = (const f4*)h1s[rb];
                const f4 A0 = hb[4*s1+0], A1 = hb[4*s1+1], A2 = hb[4*s1+2], A3 = hb[4*s1+3];
                float pre0, pre1, pre2, pre3;
                PASS1(w00,w01,w02,w03, bb0, wx00,wx01, pre0)
                PASS1(w10,w11,w12,w13, bb1, wx10,wx11, pre1)
                PASS1(w20,w21,w22,w23, bb2, wx20,wx21, pre2)
                PASS1(w30,w31,w32,w33, bb3, wx30,wx31, pre3)
                const float gi = sigm(pre0), gf = sigm(pre1);
                const float gg = tanh_(pre2), go = sigm(pre3);
                cc = fmaf(gf, cc, gi * gg);
                const float hv = go * tanh_(cc);
                if (s1 == 0) h1s[wb][u1] = hv;
            }
        } else if (t > 0) {
            PIN4(w00,w01,w02,w10); PIN4(w11,w12,w20,w21); PIN4(w22,w30,w31,w32);
            // h1(t-1) slice [8*s2, 8*s2+8) ; h2(t-2) slice [4*s2, 4*s2+4)
            const f4* hb = (const f4*)h1s[rb];
            const f4 B0 = hb[2*s2], B1 = hb[2*s2+1];
            const f4 C0 = ((const f4*)h2s[rb])[s2];
            float pre0, pre1, pre2, pre3;
            PASS2(w00,w01,w02, bb0, pre0)
            PASS2(w10,w11,w12, bb1, pre1)
            PASS2(w20,w21,w22, bb2, pre2)
            PASS2(w30,w31,w32, bb3, pre3)
            const float gi = sigm(pre0), gf = sigm(pre1);
            const float gg = tanh_(pre2), go = sigm(pre3);
            cc = fmaf(gf, cc, gi * gg);
            const float hv = go * tanh_(cc);
            if (s2 == 0) h2s[wb][u2] = hv;
        }
        __syncthreads();
    }
#undef PASS1
#undef PASS2

    // final h2(TT-1) was written at iteration t=TT into h2s[1]
    if (tid < 16) {
        float s = bfc[tid];
        const float* wr = Wfc + tid * 32;
        #pragma unroll
        for (int k = 0; k < 32; ++k) s = fmaf(wr[k], h2s[1][k], s);
        out[b * 16 + tid] = s;
    }
}

extern "C" void kernel_launch(void* const* d_in, const int* in_sizes, int n_in,
                              void* d_out, int out_size, void* d_ws, size_t ws_size,
                              hipStream_t stream) {
    const float* x    = (const float*)d_in[0];
    const float* Wih1 = (const float*)d_in[1];
    const float* Whh1 = (const float*)d_in[2];
    const float* bih1 = (const float*)d_in[3];
    const float* bhh1 = (const float*)d_in[4];
    const float* Wih2 = (const float*)d_in[5];
    const float* Whh2 = (const float*)d_in[6];
    const float* bih2 = (const float*)d_in[7];
    const float* bhh2 = (const float*)d_in[8];
    const float* Wfc  = (const float*)d_in[9];
    const float* bfc  = (const float*)d_in[10];

    hipLaunchKernelGGL(lstm_enc_kernel, dim3(BB), dim3(512), 0, stream,
        x, Wih1, Whh1, bih1, bhh1, Wih2, Whh2, bih2, bhh2, Wfc, bfc,
        (float*)d_out);
}

// Round 8
// 2647.103 us; speedup vs baseline: 7.2130x; 7.2130x over previous
//
#include <hip/hip_runtime.h>

// Encoder: 2-layer LSTM (H1=64, H2=32, IN=2), B=512, T=4096, + FC [32->16].
// R8: fp16 weights + fp16 h with v_dot2_f32_f16 (fp32 accumulate).
// R2-R7 lesson: the allocator will not keep >=128 VGPRs of fp32 weights
// resident (reload tax at 96 VGPRs, scratch-spill catastrophe when pinned).
// fp16 halves the weight footprint to 64 VGPRs/lane -> total demand ~95,
// under the allocator's natural rung, so residency needs no forcing.
// dot2 also halves dot instruction count (2 MACs/instr).
// Precision: c-state, x-path, biases, activations all fp32; only W*h products
// are fp16-in/fp32-acc. Structure = R4: waves 2,3 = L1 (2 rows/lane),
// waves 0,1 = L2 (1 row/lane) one step behind; one barrier/step.

#define TT 4096
#define BB 512

typedef float    f4  __attribute__((ext_vector_type(4)));
typedef int      i4  __attribute__((ext_vector_type(4)));
typedef _Float16 h2v __attribute__((ext_vector_type(2)));
typedef _Float16 h8  __attribute__((ext_vector_type(8)));   // 4 VGPRs

__device__ __forceinline__ float fexp2(float x){ return __builtin_amdgcn_exp2f(x); }
__device__ __forceinline__ float frcp (float x){ return __builtin_amdgcn_rcpf(x); }
__device__ __forceinline__ float sigm (float x){ return frcp(1.0f + fexp2(x * -1.4426950408889634f)); }
__device__ __forceinline__ float tanh_(float x){ return 1.0f - 2.0f * frcp(1.0f + fexp2(x * 2.8853900817779268f)); }

__device__ __forceinline__ int   rli(int v, int lane){ return __builtin_amdgcn_readlane(v, lane); }
__device__ __forceinline__ float rlf(float v, int lane){
  return __builtin_bit_cast(float, __builtin_amdgcn_readlane(__builtin_bit_cast(int, v), lane));
}
template<int CTRL>
__device__ __forceinline__ float qperm(float v){
  const int s = __builtin_bit_cast(int, v);
  return __builtin_bit_cast(float, __builtin_amdgcn_update_dpp(s, s, CTRL, 0xF, 0xF, true));
}
__device__ __forceinline__ h2v bch(int s){ return __builtin_bit_cast(h2v, s); }
__device__ __forceinline__ float fdot2(h2v a, h2v b, float c){
  return __builtin_amdgcn_fdot2(a, b, c, false);
}
__device__ __forceinline__ int pack16(float a, float b){
  h2v p; p.x = (_Float16)a; p.y = (_Float16)b;
  return __builtin_bit_cast(int, p);
}
__device__ __forceinline__ h8 cvt8(f4 a, f4 b){
  h8 r;
  r[0]=(_Float16)a.x; r[1]=(_Float16)a.y; r[2]=(_Float16)a.z; r[3]=(_Float16)a.w;
  r[4]=(_Float16)b.x; r[5]=(_Float16)b.y; r[6]=(_Float16)b.z; r[7]=(_Float16)b.w;
  return r;
}

// 4 dot2 ops of one h8 weight vector against 4 broadcast half2s (ints in SGPRs)
#define D8(W, S0, S1, S2, S3, A0, A1, A2, A3) { \
    const i4 wi_ = __builtin_bit_cast(i4, W); \
    A0 = fdot2(bch(wi_.x), bch(S0), A0); \
    A1 = fdot2(bch(wi_.y), bch(S1), A1); \
    A2 = fdot2(bch(wi_.z), bch(S2), A2); \
    A3 = fdot2(bch(wi_.w), bch(S3), A3); }

extern "C" __global__ __launch_bounds__(256) void lstm_enc_kernel(
    const float* __restrict__ x,
    const float* __restrict__ Wih1, const float* __restrict__ Whh1,
    const float* __restrict__ bih1, const float* __restrict__ bhh1,
    const float* __restrict__ Wih2, const float* __restrict__ Whh2,
    const float* __restrict__ bih2, const float* __restrict__ bhh2,
    const float* __restrict__ Wfc,  const float* __restrict__ bfc,
    float* __restrict__ out)
{
    const int tid = threadIdx.x;
    const int l   = tid & 63;
    const int wv  = __builtin_amdgcn_readfirstlane(tid >> 6);   // scalar -> s_cbranch
    const bool isL1 = (wv >= 2);
    const int b   = blockIdx.x;

    __shared__ int   h1p[2][32];   // h1 as packed half2 (32 dwords = 64 halves)
    __shared__ float h2s[2][32];   // h2 fp32

    // ---- role indices (R4 mapping) ----
    const int j1  = (wv & 1) * 32 + (l >> 1);   // L1 unit
    const int gp  = l & 1;                      // 0: rows(i,f)  1: rows(g,o)
    const int rA1 = (2 * gp) * 64 + j1;
    const int rB1 = rA1 + 64;

    const int u2   = (wv & 1) * 16 + (l >> 2);  // L2 unit
    const int g2   = l & 3;                     // gate class
    const int row2 = g2 * 32 + u2;

    const int rA_s = isL1 ? rA1 : 0;
    const int rB_s = isL1 ? rB1 : 0;
    const int r2_s = isL1 ? 0   : row2;

    // ---- weight sources (fp32), role-selected addresses ----
    const f4* pA  = (const f4*)(isL1 ? (Whh1 + rA1 * 64)      : (Wih2 + row2 * 64)); // 16 f4
    const f4* pBa = (const f4*)(isL1 ? (Whh1 + rB1 * 64)      : (Whh2 + row2 * 32)); // 8 f4
    const f4* pBb = (const f4*)(isL1 ? (Whh1 + rB1 * 64 + 32) : (Whh2 + row2 * 32)); // 8 f4

    // ---- 16 named h8 = 64 weight VGPRs (fp16) ----
    h8 wa0 = cvt8(pA[0],  pA[1]),  wa1 = cvt8(pA[2],  pA[3]);
    h8 wa2 = cvt8(pA[4],  pA[5]),  wa3 = cvt8(pA[6],  pA[7]);
    h8 wa4 = cvt8(pA[8],  pA[9]),  wa5 = cvt8(pA[10], pA[11]);
    h8 wa6 = cvt8(pA[12], pA[13]), wa7 = cvt8(pA[14], pA[15]);
    h8 wb0 = cvt8(pBa[0], pBa[1]), wb1 = cvt8(pBa[2], pBa[3]);
    h8 wb2 = cvt8(pBa[4], pBa[5]), wb3 = cvt8(pBa[6], pBa[7]);
    h8 wb4 = cvt8(pBb[0], pBb[1]), wb5 = cvt8(pBb[2], pBb[3]);
    h8 wb6 = cvt8(pBb[4], pBb[5]), wb7 = cvt8(pBb[6], pBb[7]);

    const float bbA = isL1 ? (bih1[rA_s] + bhh1[rA_s]) : (bih2[r2_s] + bhh2[r2_s]);
    const float bbB = bih1[rB_s] + bhh1[rB_s];
    const float wxA0 = Wih1[rA_s * 2 + 0], wxA1 = Wih1[rA_s * 2 + 1];
    const float wxB0 = Wih1[rB_s * 2 + 0], wxB1 = Wih1[rB_s * 2 + 1];

    const float gpf = (float)gp;                    // L1 activation blend
    const float g2t = (g2 == 2) ? 1.0f : 0.0f;      // L2 activation blend

    const float2* xb2 = (const float2*)(x + (size_t)b * (TT * 2));
    float2 vx = make_float2(0.f, 0.f), vxn = make_float2(0.f, 0.f);
    if (isL1) vxn = xb2[l];                          // chunk 0

    if (tid < 32) { h1p[0][tid] = 0; h2s[0][tid] = 0.f; h2s[1][tid] = 0.f; }
    __syncthreads();

    float cc = 0.f;   // c1 for L1 lanes, c2 for L2 lanes

    // t in [0, TT]: L1 computes step t (t<TT); L2 computes step t-1 (t>0).
    for (int t = 0; t <= TT; ++t) {
        const int rb = t & 1;
        const int wb = rb ^ 1;

        // h1(t-1) packed: lanes 0..7 hold dwords 4m..4m+3
        const i4 vh = ((const i4*)h1p[rb])[l & 7];

        // broadcast all 32 half2s of h1(t-1) into scalars
        const int B0  = rli(vh.x, 0), B1  = rli(vh.y, 0), B2  = rli(vh.z, 0), B3  = rli(vh.w, 0);
        const int B4  = rli(vh.x, 1), B5  = rli(vh.y, 1), B6  = rli(vh.z, 1), B7  = rli(vh.w, 1);
        const int B8  = rli(vh.x, 2), B9  = rli(vh.y, 2), B10 = rli(vh.z, 2), B11 = rli(vh.w, 2);
        const int B12 = rli(vh.x, 3), B13 = rli(vh.y, 3), B14 = rli(vh.z, 3), B15 = rli(vh.w, 3);
        const int B16 = rli(vh.x, 4), B17 = rli(vh.y, 4), B18 = rli(vh.z, 4), B19 = rli(vh.w, 4);
        const int B20 = rli(vh.x, 5), B21 = rli(vh.y, 5), B22 = rli(vh.z, 5), B23 = rli(vh.w, 5);
        const int B24 = rli(vh.x, 6), B25 = rli(vh.y, 6), B26 = rli(vh.z, 6), B27 = rli(vh.w, 6);
        const int B28 = rli(vh.x, 7), B29 = rli(vh.y, 7), B30 = rli(vh.z, 7), B31 = rli(vh.w, 7);

        if (isL1) {
            if (t < TT) {
                if ((t & 63) == 0) {
                    vx = vxn;
                    if (t + 64 < TT) vxn = xb2[(t >> 6) * 64 + 64 + l];
                }
                const float xx0 = rlf(vx.x, t & 63);
                const float xx1 = rlf(vx.y, t & 63);

                float aA0=0.f,aA1=0.f,aA2=0.f,aA3=0.f;
                float aB0=0.f,aB1=0.f,aB2=0.f,aB3=0.f;
                D8(wa0, B0,B1,B2,B3,     aA0,aA1,aA2,aA3)
                D8(wa1, B4,B5,B6,B7,     aA0,aA1,aA2,aA3)
                D8(wa2, B8,B9,B10,B11,   aA0,aA1,aA2,aA3)
                D8(wa3, B12,B13,B14,B15, aA0,aA1,aA2,aA3)
                D8(wa4, B16,B17,B18,B19, aA0,aA1,aA2,aA3)
                D8(wa5, B20,B21,B22,B23, aA0,aA1,aA2,aA3)
                D8(wa6, B24,B25,B26,B27, aA0,aA1,aA2,aA3)
                D8(wa7, B28,B29,B30,B31, aA0,aA1,aA2,aA3)
                D8(wb0, B0,B1,B2,B3,     aB0,aB1,aB2,aB3)
                D8(wb1, B4,B5,B6,B7,     aB0,aB1,aB2,aB3)
                D8(wb2, B8,B9,B10,B11,   aB0,aB1,aB2,aB3)
                D8(wb3, B12,B13,B14,B15, aB0,aB1,aB2,aB3)
                D8(wb4, B16,B17,B18,B19, aB0,aB1,aB2,aB3)
                D8(wb5, B20,B21,B22,B23, aB0,aB1,aB2,aB3)
                D8(wb6, B24,B25,B26,B27, aB0,aB1,aB2,aB3)
                D8(wb7, B28,B29,B30,B31, aB0,aB1,aB2,aB3)
                const float preA = ((aA0+aA1)+(aA2+aA3)) + fmaf(wxA0, xx0, fmaf(wxA1, xx1, bbA));
                const float preB = ((aB0+aB1)+(aB2+aB3)) + fmaf(wxB0, xx0, fmaf(wxB1, xx1, bbB));

                // actA: sigm (gp=0, i-row) or tanh (gp=1, g-row); tanh(x)=2*sigm(2x)-1
                const float pa   = fmaf(gpf, preA, preA);
                const float sa   = sigm(pa);
                const float actA = fmaf(gpf, sa - 1.0f, sa);
                const float actB = sigm(preB);

                const float pA_ = qperm<0xB1>(actA);   // pair swap in quad
                const float pB_ = qperm<0xB1>(actB);
                const float gi = gp ? pA_  : actA;
                const float gf = gp ? pB_  : actB;
                const float gg = gp ? actA : pA_;
                const float go = gp ? actB : pB_;
                cc = fmaf(gf, cc, gi * gg);
                const float h1v = go * tanh_(cc);

                // pack pair (unit 2u, 2u+1): lane 4u gets partner from lane 4u+2
                const float h1n = qperm<0x4E>(h1v);    // [2,3,0,1]
                if ((l & 3) == 0) h1p[wb][(wv & 1) * 16 + (l >> 2)] = pack16(h1v, h1n);
            }
        } else if (t > 0) {
            // layer 2, step t-1: h2(t-2) fp32, lanes 0..7 hold h2[4m..4m+3]
            const f4 vc = ((const f4*)h2s[rb])[l & 7];
            const int c0 = pack16(vc.x, vc.y);
            const int c1 = pack16(vc.z, vc.w);
            const int C0  = rli(c0, 0), C1  = rli(c1, 0);
            const int C2  = rli(c0, 1), C3  = rli(c1, 1);
            const int C4  = rli(c0, 2), C5  = rli(c1, 2);
            const int C6  = rli(c0, 3), C7  = rli(c1, 3);
            const int C8  = rli(c0, 4), C9  = rli(c1, 4);
            const int C10 = rli(c0, 5), C11 = rli(c1, 5);
            const int C12 = rli(c0, 6), C13 = rli(c1, 6);
            const int C14 = rli(c0, 7), C15 = rli(c1, 7);

            float a0=0.f,a1=0.f,a2=0.f,a3=0.f;
            D8(wa0, B0,B1,B2,B3,     a0,a1,a2,a3)
            D8(wa1, B4,B5,B6,B7,     a0,a1,a2,a3)
            D8(wa2, B8,B9,B10,B11,   a0,a1,a2,a3)
            D8(wa3, B12,B13,B14,B15, a0,a1,a2,a3)
            D8(wa4, B16,B17,B18,B19, a0,a1,a2,a3)
            D8(wa5, B20,B21,B22,B23, a0,a1,a2,a3)
            D8(wa6, B24,B25,B26,B27, a0,a1,a2,a3)
            D8(wa7, B28,B29,B30,B31, a0,a1,a2,a3)
            D8(wb0, C0,C1,C2,C3,     a0,a1,a2,a3)
            D8(wb1, C4,C5,C6,C7,     a0,a1,a2,a3)
            D8(wb2, C8,C9,C10,C11,   a0,a1,a2,a3)
            D8(wb3, C12,C13,C14,C15, a0,a1,a2,a3)
            const float pre2 = bbA + ((a0+a1)+(a2+a3));

            const float p2   = fmaf(g2t, pre2, pre2);
            const float s2v  = sigm(p2);
            const float act2 = fmaf(g2t, s2v - 1.0f, s2v);

            const float i2 = qperm<0x00>(act2);
            const float f2 = qperm<0x55>(act2);
            const float g2v= qperm<0xAA>(act2);
            const float o2 = qperm<0xFF>(act2);
            cc = fmaf(f2, cc, i2 * g2v);
            const float h2v_ = o2 * tanh_(cc);
            if (g2 == 0) h2s[wb][u2] = h2v_;
        }
        __syncthreads();
    }

    // final h2(TT-1) written at t=TT into h2s[1]
    if (tid < 16) {
        float s = bfc[tid];
        const float* wr = Wfc + tid * 32;
        #pragma unroll
        for (int k = 0; k < 32; ++k) s = fmaf(wr[k], h2s[1][k], s);
        out[b * 16 + tid] = s;
    }
}

extern "C" void kernel_launch(void* const* d_in, const int* in_sizes, int n_in,
                              void* d_out, int out_size, void* d_ws, size_t ws_size,
                              hipStream_t stream) {
    const float* x    = (const float*)d_in[0];
    const float* Wih1 = (const float*)d_in[1];
    const float* Whh1 = (const float*)d_in[2];
    const float* bih1 = (const float*)d_in[3];
    const float* bhh1 = (const float*)d_in[4];
    const float* Wih2 = (const float*)d_in[5];
    const float* Whh2 = (const float*)d_in[6];
    const float* bih2 = (const float*)d_in[7];
    const float* bhh2 = (const float*)d_in[8];
    const float* Wfc  = (const float*)d_in[9];
    const float* bfc  = (const float*)d_in[10];

    hipLaunchKernelGGL(lstm_enc_kernel, dim3(BB), dim3(256), 0, stream,
        x, Wih1, Whh1, bih1, bhh1, Wih2, Whh2, bih2, bhh2, Wfc, bfc,
        (float*)d_out);
}

// Round 9
// 2145.484 us; speedup vs baseline: 8.8995x; 1.2338x over previous
//
#include <hip/hip_runtime.h>

// Encoder: 2-layer LSTM (H1=64, H2=32, IN=2), B=512, T=4096, + FC [32->16].
// R9: K-sliced fp16 dot2 design. R8 analysis: VALU-busy ~1160 cyc/step only
// matches if the 82 v_readlane broadcasts/step run at ~1/4 rate -> kernel is
// broadcast-bound. Fix: slice K across a lane PAIR (L1) / QUAD (L2) so dot2
// operands are per-lane ds_read data (2/4-way aliased b128 = free), reduce
// with full-rate DPP adds, gate-exchange shuffles disappear (all 4 pre-acts
// end up in every lane). h1(64) ++ h2(32) live as one contiguous 96-half
// packed-fp16 LDS buffer so the L2 slice is a clean 3x b128 read.
//   waves 2,3 = L1: pair = unit (u1), lane s1 = K-half (32 halves/row x 4 rows)
//   waves 0,3 = L2: quad = unit (u2), lane s2 = K-quarter (24 halves/row x 4),
//                   one step behind L1; one barrier per step.
// Bias & x-weights zeroed on non-slice-0 lanes -> counted once after reduce.

#define TT 4096
#define BB 512

typedef float    f4  __attribute__((ext_vector_type(4)));
typedef int      i4  __attribute__((ext_vector_type(4)));
typedef _Float16 h2v __attribute__((ext_vector_type(2)));
typedef _Float16 h8  __attribute__((ext_vector_type(8)));   // 4 VGPRs

__device__ __forceinline__ float fexp2(float x){ return __builtin_amdgcn_exp2f(x); }
__device__ __forceinline__ float frcp (float x){ return __builtin_amdgcn_rcpf(x); }
__device__ __forceinline__ float sigm (float x){ return frcp(1.0f + fexp2(x * -1.4426950408889634f)); }
__device__ __forceinline__ float tanh_(float x){ return 1.0f - 2.0f * frcp(1.0f + fexp2(x * 2.8853900817779268f)); }

__device__ __forceinline__ float rlf(float v, int lane){
  return __builtin_bit_cast(float, __builtin_amdgcn_readlane(__builtin_bit_cast(int, v), lane));
}
// DPP quad-perm (VALU, full-rate). 0xB1=[1,0,3,2], 0x4E=[2,3,0,1], bcasts 0x00/0x55/0xAA/0xFF.
template<int CTRL>
__device__ __forceinline__ float qperm(float v){
  const int s = __builtin_bit_cast(int, v);
  return __builtin_bit_cast(float, __builtin_amdgcn_update_dpp(s, s, CTRL, 0xF, 0xF, true));
}
__device__ __forceinline__ h2v bch(int s){ return __builtin_bit_cast(h2v, s); }
// 8-wide fp16 dot with fp32 accumulate: 4x v_dot2_f32_f16
__device__ __forceinline__ float dot8(h8 a, h8 b, float c){
  const i4 ai = __builtin_bit_cast(i4, a);
  const i4 bi = __builtin_bit_cast(i4, b);
  c = __builtin_amdgcn_fdot2(bch(ai.x), bch(bi.x), c, false);
  c = __builtin_amdgcn_fdot2(bch(ai.y), bch(bi.y), c, false);
  c = __builtin_amdgcn_fdot2(bch(ai.z), bch(bi.z), c, false);
  c = __builtin_amdgcn_fdot2(bch(ai.w), bch(bi.w), c, false);
  return c;
}
__device__ __forceinline__ h8 cvt8(f4 a, f4 b){
  h8 r;
  r[0]=(_Float16)a.x; r[1]=(_Float16)a.y; r[2]=(_Float16)a.z; r[3]=(_Float16)a.w;
  r[4]=(_Float16)b.x; r[5]=(_Float16)b.y; r[6]=(_Float16)b.z; r[7]=(_Float16)b.w;
  return r;
}
__device__ __forceinline__ h8 ldh8(const float* p){
  const f4* q = (const f4*)p;
  return cvt8(q[0], q[1]);
}

extern "C" __global__ __launch_bounds__(256) void lstm_enc_kernel(
    const float* __restrict__ x,
    const float* __restrict__ Wih1, const float* __restrict__ Whh1,
    const float* __restrict__ bih1, const float* __restrict__ bhh1,
    const float* __restrict__ Wih2, const float* __restrict__ Whh2,
    const float* __restrict__ bih2, const float* __restrict__ bhh2,
    const float* __restrict__ Wfc,  const float* __restrict__ bfc,
    float* __restrict__ out)
{
    const int tid = threadIdx.x;
    const int l   = tid & 63;
    const int wv  = __builtin_amdgcn_readfirstlane(tid >> 6);   // scalar -> s_cbranch
    const bool isL1 = (wv >= 2);
    const int b   = blockIdx.x;

    // hh[buf][0:64) = h1 halves, hh[buf][64:96) = h2 halves
    __shared__ __align__(16) _Float16 hh[2][96];

    // L1: pair = unit; s1 = K-half. L2: quad = unit; s2 = K-quarter.
    const int u1 = (wv & 1) * 32 + (l >> 1);
    const int s1 = l & 1;
    const int u2 = (wv & 1) * 16 + (l >> 2);
    const int s2 = l & 3;

    // ---- weights: 16 named h8 = 64 VGPRs (L2 uses 12; slot3 = dup) ----
    h8 w00,w01,w02,w03, w10,w11,w12,w13, w20,w21,w22,w23, w30,w31,w32,w33;
    float bb0,bb1,bb2,bb3;
    float wx00,wx01, wx10,wx11, wx20,wx21, wx30,wx31;

    // L1 row g: Whh1[g*64+u1][32*s1 .. +32) (4 h8 slots)
    // L2 row g: concat(Wih2[g*32+u2][0:64], Whh2[g*32+u2][0:32]) floats
    //           [24*s2 .. +24) (3 h8 slots; 8-float slots never straddle 64)
#define LWROW(G, W0,W1,W2,W3, BB_, WX0_, WX1_) { \
    const int rg1 = (G)*64 + u1; \
    const int rg2 = (G)*32 + u2; \
    const float* a1  = Whh1 + rg1*64 + 32*s1; \
    const float* i2p = Wih2 + rg2*64; \
    const float* h2p = Whh2 + rg2*32; \
    const int f0 = 24*s2, f1 = f0+8, f2c = f0+16; \
    const float* q0 = isL1 ? (a1+ 0) : (f0  < 64 ? i2p+f0  : h2p+f0 -64); \
    const float* q1 = isL1 ? (a1+ 8) : (f1  < 64 ? i2p+f1  : h2p+f1 -64); \
    const float* q2 = isL1 ? (a1+16) : (f2c < 64 ? i2p+f2c : h2p+f2c-64); \
    const float* q3 = isL1 ? (a1+24) : q2; \
    W0 = ldh8(q0); W1 = ldh8(q1); W2 = ldh8(q2); W3 = ldh8(q3); \
    const float bb1v = bih1[rg1] + bhh1[rg1]; \
    const float bb2v = bih2[rg2] + bhh2[rg2]; \
    BB_  = isL1 ? (s1 ? 0.f : bb1v) : (s2 ? 0.f : bb2v); \
    WX0_ = (isL1 && !s1) ? Wih1[rg1*2]   : 0.f; \
    WX1_ = (isL1 && !s1) ? Wih1[rg1*2+1] : 0.f; }

    LWROW(0, w00,w01,w02,w03, bb0, wx00,wx01)
    LWROW(1, w10,w11,w12,w13, bb1, wx10,wx11)
    LWROW(2, w20,w21,w22,w23, bb2, wx20,wx21)
    LWROW(3, w30,w31,w32,w33, bb3, wx30,wx31)
#undef LWROW

    const float sf  = (float)s1;                 // L1 tanh-blend flag (g-row on odd lane)
    const float g2t = (s2 == 2) ? 1.f : 0.f;     // L2 tanh-blend flag

    const float2* xb2 = (const float2*)(x + (size_t)b * (TT * 2));
    float2 vx = make_float2(0.f, 0.f), vxn = make_float2(0.f, 0.f);
    if (isL1) vxn = xb2[l];                      // chunk 0 (64 steps of x)

    if (tid < 96) ((int*)hh)[tid] = 0;           // zero both buffers (192 halves)
    __syncthreads();

    float cc = 0.f;   // c1 (L1 lanes) / c2 (L2 lanes); redundant per pair/quad

    // t in [0, TT]: L1 computes step t (t<TT); L2 computes step t-1 (t>0).
    for (int t = 0; t <= TT; ++t) {
        const int rb = t & 1;
        const int wb = rb ^ 1;
        const i4* hb = (const i4*)hh[rb];

        if (isL1) {
            if (t < TT) {
                if ((t & 63) == 0) {
                    vx = vxn;
                    if (t + 64 < TT) vxn = xb2[(t >> 6) * 64 + 64 + l];
                }
                const float xx0 = rlf(vx.x, t & 63);
                const float xx1 = rlf(vx.y, t & 63);

                // h1(t-1) K-half slice: halves [32*s1, 32*s1+32) (2-way alias)
                const h8 H0 = __builtin_bit_cast(h8, hb[4*s1+0]);
                const h8 H1 = __builtin_bit_cast(h8, hb[4*s1+1]);
                const h8 H2 = __builtin_bit_cast(h8, hb[4*s1+2]);
                const h8 H3 = __builtin_bit_cast(h8, hb[4*s1+3]);

                float r0 = bb0, r1 = bb1, r2 = bb2, r3 = bb3;
                r0 = dot8(w00,H0,r0); r0 = dot8(w01,H1,r0); r0 = dot8(w02,H2,r0); r0 = dot8(w03,H3,r0);
                r1 = dot8(w10,H0,r1); r1 = dot8(w11,H1,r1); r1 = dot8(w12,H2,r1); r1 = dot8(w13,H3,r1);
                r2 = dot8(w20,H0,r2); r2 = dot8(w21,H1,r2); r2 = dot8(w22,H2,r2); r2 = dot8(w23,H3,r2);
                r3 = dot8(w30,H0,r3); r3 = dot8(w31,H1,r3); r3 = dot8(w32,H2,r3); r3 = dot8(w33,H3,r3);
                // x/bias only on s1==0 lanes (wx/bb zeroed elsewhere)
                r0 = fmaf(wx00, xx0, fmaf(wx01, xx1, r0));
                r1 = fmaf(wx10, xx0, fmaf(wx11, xx1, r1));
                r2 = fmaf(wx20, xx0, fmaf(wx21, xx1, r2));
                r3 = fmaf(wx30, xx0, fmaf(wx31, xx1, r3));
                // pair reduce -> both lanes hold full 64-dots for all 4 gates
                r0 += qperm<0xB1>(r0); r1 += qperm<0xB1>(r1);
                r2 += qperm<0xB1>(r2); r3 += qperm<0xB1>(r3);

                // split activations across the pair: even does sigm(i),sigm(f);
                // odd does tanh(g),sigm(o); exchange with 0xB1
                const float pe0 = s1 ? r2 : r0;
                const float pe1 = s1 ? r3 : r1;
                const float pb  = fmaf(sf, pe0, pe0);        // x or 2x
                const float sa  = sigm(pb);
                const float v0  = fmaf(sf, sa - 1.f, sa);    // sigm or tanh
                const float v1  = sigm(pe1);
                const float o0  = qperm<0xB1>(v0);
                const float o1  = qperm<0xB1>(v1);
                const float gi = s1 ? o0 : v0, gf = s1 ? o1 : v1;
                const float gg = s1 ? v0 : o0, go = s1 ? v1 : o1;
                cc = fmaf(gf, cc, gi * gg);
                const float h1v = go * tanh_(cc);
                if (!s1) hh[wb][u1] = (_Float16)h1v;         // ds_write_b16
            }
        } else if (t > 0) {
            // L2, step t-1: slice halves [24*s2, 24*s2+24) of h1(t-1)++h2(t-2)
            const h8 H0 = __builtin_bit_cast(h8, hb[3*s2+0]);
            const h8 H1 = __builtin_bit_cast(h8, hb[3*s2+1]);
            const h8 H2 = __builtin_bit_cast(h8, hb[3*s2+2]);

            float r0 = bb0, r1 = bb1, r2 = bb2, r3 = bb3;
            r0 = dot8(w00,H0,r0); r0 = dot8(w01,H1,r0); r0 = dot8(w02,H2,r0);
            r1 = dot8(w10,H0,r1); r1 = dot8(w11,H1,r1); r1 = dot8(w12,H2,r1);
            r2 = dot8(w20,H0,r2); r2 = dot8(w21,H1,r2); r2 = dot8(w22,H2,r2);
            r3 = dot8(w30,H0,r3); r3 = dot8(w31,H1,r3); r3 = dot8(w32,H2,r3);
            // quad reduce -> every lane holds full 96-dots for all 4 gates
            r0 += qperm<0xB1>(r0); r0 += qperm<0x4E>(r0);
            r1 += qperm<0xB1>(r1); r1 += qperm<0x4E>(r1);
            r2 += qperm<0xB1>(r2); r2 += qperm<0x4E>(r2);
            r3 += qperm<0xB1>(r3); r3 += qperm<0x4E>(r3);

            // lane s2 activates gate s2, then quad-broadcast gathers
            const float pre = (s2==0) ? r0 : (s2==1) ? r1 : (s2==2) ? r2 : r3;
            const float p2  = fmaf(g2t, pre, pre);
            const float sv  = sigm(p2);
            const float act = fmaf(g2t, sv - 1.f, sv);
            const float i2 = qperm<0x00>(act);
            const float f2 = qperm<0x55>(act);
            const float gv = qperm<0xAA>(act);
            const float o2 = qperm<0xFF>(act);
            cc = fmaf(f2, cc, i2 * gv);
            const float h2v_ = o2 * tanh_(cc);
            if (s2 == 0) hh[wb][64 + u2] = (_Float16)h2v_;   // ds_write_b16
        }
        __syncthreads();
    }

    // final h2(TT-1) was written at t=TT into hh[1][64:96)
    if (tid < 16) {
        float s = bfc[tid];
        const float* wr = Wfc + tid * 32;
        #pragma unroll
        for (int k = 0; k < 32; ++k) s = fmaf(wr[k], (float)hh[1][64 + k], s);
        out[b * 16 + tid] = s;
    }
}

extern "C" void kernel_launch(void* const* d_in, const int* in_sizes, int n_in,
                              void* d_out, int out_size, void* d_ws, size_t ws_size,
                              hipStream_t stream) {
    const float* x    = (const float*)d_in[0];
    const float* Wih1 = (const float*)d_in[1];
    const float* Whh1 = (const float*)d_in[2];
    const float* bih1 = (const float*)d_in[3];
    const float* bhh1 = (const float*)d_in[4];
    const float* Wih2 = (const float*)d_in[5];
    const float* Whh2 = (const float*)d_in[6];
    const float* bih2 = (const float*)d_in[7];
    const float* bhh2 = (const float*)d_in[8];
    const float* Wfc  = (const float*)d_in[9];
    const float* bfc  = (const float*)d_in[10];

    hipLaunchKernelGGL(lstm_enc_kernel, dim3(BB), dim3(256), 0, stream,
        x, Wih1, Whh1, bih1, bhh1, Wih2, Whh2, bih2, bhh2, Wfc, bfc,
        (float*)d_out);
}